// Round 3
// baseline (143.803 us; speedup 1.0000x reference)
//
#include <hip/hip_runtime.h>

// pos/seq_lens fill for ragged batch metadata.
// d_out layout (int32): [0, num_tokens) = pos, [num_tokens, +max_num_reqs) = seq_lens.
//
// R3: kill the per-thread binary search (R2 post-mortem: 43 us @ 1.5 TB/s,
// latency-bound on 13 dependent qsl loads per thread in a single occupancy
// round -- NOT store-bound; harness fill does 6.4 TB/s).
//  - Kernel 1: per 2048-token tile, precompute starting request index into
//    d_ws (8192 independent searches, ~3 us) + write seq_lens.
//  - Kernel 2: 8192 blocks x 256 thr, 2048 tokens/block (2 lane-contiguous
//    int4 stores/thread). Block reads tile_req[blockIdx] (L2 broadcast),
//    threads advance <=~1 boundary, store. 32 blocks/CU -> 4 occupancy
//    rounds so search/advance latency overlaps store drain.

#define TPB 256
#define TILE_TOK 2048                         // tokens per kernel-2 block
#define SEQ_PER_BLOCK (TPB * 4)               // 1024

// ---------- kernel 1: tile starts + seq_lens ----------
__global__ __launch_bounds__(TPB) void prep_kernel(
    const int* __restrict__ idx_mapping,
    const int* __restrict__ qsl,          // [num_reqs+1]
    const int* __restrict__ nct,          // [max_num_reqs]
    int* __restrict__ tile_req,           // [num_tiles] (in d_ws)
    int* __restrict__ seq_out,            // [max_num_reqs]
    int num_reqs, int max_num_reqs, int num_tokens,
    int num_tiles, int tile_blocks)
{
    int b = blockIdx.x;
    if (b < tile_blocks) {
        int tile = b * TPB + (int)threadIdx.x;
        if (tile >= num_tiles) return;
        long long tl = (long long)tile * TILE_TOK;
        int t = (tl >= num_tokens) ? (num_tokens - 1) : (int)tl;
        // upper_bound: last r in [0, num_reqs] with qsl[r] <= t
        int l = 0, h = num_reqs + 1;
        while (h - l > 1) {
            int mid = (l + h) >> 1;
            if (qsl[mid] <= t) l = mid; else h = mid;
        }
        tile_req[tile] = l;
        return;
    }
    // ---- seq_lens ----
    int i = (b - tile_blocks) * SEQ_PER_BLOCK + (int)threadIdx.x * 4;
    if (i >= max_num_reqs) return;
    if (i + 4 <= max_num_reqs) {
        int4 v;
        int* vp = (int*)&v;
        #pragma unroll
        for (int k = 0; k < 4; ++k) {
            int idx = i + k;
            int val = 0;
            if (idx < num_reqs)
                val = nct[idx_mapping[idx]] + (qsl[idx + 1] - qsl[idx]);
            vp[k] = val;
        }
        *(int4*)(seq_out + i) = v;
    } else {
        for (int idx = i; idx < max_num_reqs; ++idx) {
            int val = 0;
            if (idx < num_reqs)
                val = nct[idx_mapping[idx]] + (qsl[idx + 1] - qsl[idx]);
            seq_out[idx] = val;
        }
    }
}

// ---------- kernel 2: pos fill, no binary search ----------
__global__ __launch_bounds__(TPB) void pos_kernel(
    const int* __restrict__ idx_mapping,
    const int* __restrict__ qsl,          // [num_reqs+1]
    const int* __restrict__ nct,          // [max_num_reqs]
    const int* __restrict__ tile_req,     // [num_tiles]
    int* __restrict__ pos_out,            // [num_tokens]
    int num_reqs, int num_tokens)
{
    int tile = blockIdx.x;
    long long bsl = (long long)tile * TILE_TOK;
    int blockStart = (int)bsl;
    int tid = (int)threadIdx.x;

    int tfirst = blockStart + tid * 4;
    if (tfirst >= num_tokens) return;

    int r = tile_req[tile];                // uniform, L2-broadcast
    int next = qsl[r + 1];
    int base = nct[idx_mapping[r]] - qsl[r];

    // advance to this thread's first token (usually 0-1 iterations)
    while (tfirst >= next) {
        ++r;
        next = qsl[r + 1];
        base = nct[idx_mapping[r]] - qsl[r];
    }

    #pragma unroll
    for (int g = 0; g < 2; ++g) {
        int tc = blockStart + g * (TPB * 4) + tid * 4;
        if (tc >= num_tokens) return;
        int4 v;
        int* vp = (int*)&v;
        int t = tc;
        #pragma unroll
        for (int k = 0; k < 4; ++k) {
            while (t >= next) {            // handles empty requests too
                ++r;
                next = qsl[r + 1];
                base = nct[idx_mapping[r]] - qsl[r];
            }
            vp[k] = base + t;
            ++t;
        }
        if (tc + 4 <= num_tokens) {
            *(int4*)(pos_out + tc) = v;
        } else {
            for (int k = 0; k < num_tokens - tc; ++k) pos_out[tc + k] = vp[k];
        }
    }
}

extern "C" void kernel_launch(void* const* d_in, const int* in_sizes, int n_in,
                              void* d_out, int out_size, void* d_ws, size_t ws_size,
                              hipStream_t stream) {
    const int* idx_mapping = (const int*)d_in[0];
    const int* qsl         = (const int*)d_in[1];
    const int* nct         = (const int*)d_in[2];
    // d_in[3] (pos buffer) and d_in[4] (seq_lens buffer) are unused inputs.

    int num_reqs     = in_sizes[0];
    int max_num_reqs = in_sizes[2];
    int num_tokens   = in_sizes[3];

    int* out = (int*)d_out;
    int* pos_out = out;
    int* seq_out = out + num_tokens;
    int* tile_req = (int*)d_ws;

    int num_tiles   = (int)(((long long)num_tokens + TILE_TOK - 1) / TILE_TOK); // 8192
    int tile_blocks = (num_tiles + TPB - 1) / TPB;                              // 32
    int seq_blocks  = (max_num_reqs + SEQ_PER_BLOCK - 1) / SEQ_PER_BLOCK;       // 16

    prep_kernel<<<dim3(tile_blocks + seq_blocks), dim3(TPB), 0, stream>>>(
        idx_mapping, qsl, nct, tile_req, seq_out,
        num_reqs, max_num_reqs, num_tokens, num_tiles, tile_blocks);

    pos_kernel<<<dim3(num_tiles), dim3(TPB), 0, stream>>>(
        idx_mapping, qsl, nct, tile_req, pos_out, num_reqs, num_tokens);
}

// Round 5
// 119.436 us; speedup vs baseline: 1.2040x; 1.2040x over previous
//
#include <hip/hip_runtime.h>

// pos/seq_lens fill for ragged batch metadata.
// d_out layout (int32): [0, num_tokens) = pos, [num_tokens, +max_num_reqs) = seq_lens.
//
// R5 = R4 with the nontemporal-store type fixed (ext_vector_type, not
// HIP_vector_type). Design rationale (R3 post-mortem): pos writes ran at
// ~1.5 TB/s vs 6.4 TB/s harness fill; search removal didn't help, so the
// cost is in-loop dependent gathers + L2 write-allocate churn.
//  - prep kernel: (a) base_req[r] = nct[idx_mapping[r]] - qsl[r],
//    (b) tile_req[j] = owning request of token j*1024, (c) seq_lens.
//  - hot kernel (16384 blocks x 256 thr, 1 int4/thread): tile inside one
//    request (~60%) -> pure stream pos = t + scalar_base, zero per-lane
//    loads; else short linear advance via qsl/base_req.
//  - nontemporal 16B stores: pos is write-only, never re-read.

#define TPB 256
#define TILE_TOK 1024                       // tokens per hot block (1 int4/thread)
#define SEQ_PER_BLOCK (TPB * 4)             // 1024

typedef int vint4 __attribute__((ext_vector_type(4)));

// ---------- prep: base_req + tile_req + seq_lens ----------
__global__ __launch_bounds__(TPB) void prep_kernel(
    const int* __restrict__ idx_mapping,
    const int* __restrict__ qsl,          // [num_reqs+1]
    const int* __restrict__ nct,          // [max_num_reqs]
    int* __restrict__ tile_req,           // [num_tiles+1]   (d_ws)
    int* __restrict__ base_req,           // [num_reqs]      (d_ws)
    int* __restrict__ seq_out,            // [max_num_reqs]
    int num_reqs, int max_num_reqs, int num_tokens,
    int bound_count, int bound_blocks)
{
    int b = blockIdx.x;
    if (b < bound_blocks) {
        int j = b * TPB + (int)threadIdx.x;
        if (j >= bound_count) return;
        long long tl = (long long)j * TILE_TOK;
        int t = (tl >= num_tokens) ? (num_tokens - 1) : (int)tl;
        // last r in [0, num_reqs] with qsl[r] <= t  (== searchsorted-right - 1)
        int l = 0, h = num_reqs + 1;
        while (h - l > 1) {
            int mid = (l + h) >> 1;
            if (qsl[mid] <= t) l = mid; else h = mid;
        }
        tile_req[j] = l;
        return;
    }
    // ---- base_req + seq_lens ----
    int i = (b - bound_blocks) * SEQ_PER_BLOCK + (int)threadIdx.x * 4;
    if (i >= max_num_reqs) return;
    vint4 v;
    #pragma unroll
    for (int k = 0; k < 4; ++k) {
        int idx = i + k;
        int val = 0;
        if (idx < num_reqs) {
            int q0 = qsl[idx], q1 = qsl[idx + 1];
            int nb = nct[idx_mapping[idx]];
            base_req[idx] = nb - q0;
            val = nb + (q1 - q0);
        }
        v[k] = val;
    }
    if (i + 4 <= max_num_reqs) {
        *(vint4*)(seq_out + i) = v;
    } else {
        for (int k = 0; k < max_num_reqs - i; ++k) seq_out[i + k] = v[k];
    }
}

// ---------- hot: pos fill ----------
__global__ __launch_bounds__(TPB) void pos_kernel(
    const int* __restrict__ qsl,          // [num_reqs+1]
    const int* __restrict__ tile_req,     // [num_tiles+1]
    const int* __restrict__ base_req,     // [num_reqs]
    int* __restrict__ pos_out,            // [num_tokens]
    int num_tokens)
{
    int tile = blockIdx.x;
    int t = tile * TILE_TOK + (int)threadIdx.x * 4;
    if (t >= num_tokens) return;

    int r0 = tile_req[tile];              // wave-uniform (s_load)
    int r1 = tile_req[tile + 1];
    vint4 v;

    if (r0 == r1) {
        // whole tile inside one request: pure stream
        int base = base_req[r0];          // wave-uniform
        v[0] = t + base; v[1] = t + 1 + base;
        v[2] = t + 2 + base; v[3] = t + 3 + base;
    } else {
        int r = r0;
        while (qsl[r + 1] <= t) ++r;      // advance to this thread's request
        int next = qsl[r + 1];
        int base = base_req[r];
        #pragma unroll
        for (int k = 0; k < 4; ++k) {
            int tk = t + k;
            while (tk >= next) {          // handles empty requests too
                ++r;
                next = qsl[r + 1];
                base = base_req[r];
            }
            v[k] = base + tk;
        }
    }

    if (t + 4 <= num_tokens) {
        __builtin_nontemporal_store(v, (vint4*)(pos_out + t));
    } else {
        for (int k = 0; k < num_tokens - t; ++k) pos_out[t + k] = v[k];
    }
}

extern "C" void kernel_launch(void* const* d_in, const int* in_sizes, int n_in,
                              void* d_out, int out_size, void* d_ws, size_t ws_size,
                              hipStream_t stream) {
    const int* idx_mapping = (const int*)d_in[0];
    const int* qsl         = (const int*)d_in[1];
    const int* nct         = (const int*)d_in[2];
    // d_in[3] (pos buffer) and d_in[4] (seq_lens buffer) are unused inputs.

    int num_reqs     = in_sizes[0];
    int max_num_reqs = in_sizes[2];
    int num_tokens   = in_sizes[3];

    int* out = (int*)d_out;
    int* pos_out = out;
    int* seq_out = out + num_tokens;

    int num_tiles   = (int)(((long long)num_tokens + TILE_TOK - 1) / TILE_TOK); // 16384
    int bound_count = num_tiles + 1;                                            // 16385
    int* tile_req = (int*)d_ws;
    int* base_req = tile_req + (bound_count + 3) / 4 * 4;

    int bound_blocks = (bound_count + TPB - 1) / TPB;                           // 65
    int seq_blocks   = (max_num_reqs + SEQ_PER_BLOCK - 1) / SEQ_PER_BLOCK;      // 16

    prep_kernel<<<dim3(bound_blocks + seq_blocks), dim3(TPB), 0, stream>>>(
        idx_mapping, qsl, nct, tile_req, base_req, seq_out,
        num_reqs, max_num_reqs, num_tokens, bound_count, bound_blocks);

    pos_kernel<<<dim3(num_tiles), dim3(TPB), 0, stream>>>(
        qsl, tile_req, base_req, pos_out, num_tokens);
}